// Round 1
// baseline (909.462 us; speedup 1.0000x reference)
//
#include <hip/hip_runtime.h>

// ---------------------------------------------------------------------------
// Fused MHA: qkv = x@Wqkv+b ; causal attention ; out = attn@Wproj+b
// B=4, T=2048, C=2048, H=16, D=128. fp32 in/out, bf16 MFMA internally.
// ---------------------------------------------------------------------------

typedef __bf16 bf16;
typedef __bf16 bf16x8 __attribute__((ext_vector_type(8)));
typedef __bf16 bf16x4 __attribute__((ext_vector_type(4)));
typedef float f32x4 __attribute__((ext_vector_type(4)));

__device__ __forceinline__ void gload_lds16(const void* g, void* l) {
  __builtin_amdgcn_global_load_lds(
      (const __attribute__((address_space(1))) void*)g,
      (__attribute__((address_space(3))) void*)l, 16, 0, 0);
}

// ---------------------------------------------------------------------------
// cast fp32 -> bf16, 8 elems/thread
__global__ __launch_bounds__(256) void cast_f32_bf16(
    const float* __restrict__ in, bf16* __restrict__ out, int n8) {
  int i = blockIdx.x * 256 + threadIdx.x;
  if (i >= n8) return;
  const float4* p = (const float4*)in + (size_t)i * 2;
  float4 a = p[0], b = p[1];
  bf16x8 o8 = {(bf16)a.x, (bf16)a.y, (bf16)a.z, (bf16)a.w,
               (bf16)b.x, (bf16)b.y, (bf16)b.z, (bf16)b.w};
  *(bf16x8*)(out + (size_t)i * 8) = o8;
}

// ---------------------------------------------------------------------------
// W [R][C] fp32  ->  WT [C][R] bf16   (32x32 LDS tile transpose)
__global__ __launch_bounds__(256) void transpose_cast(
    const float* __restrict__ in, bf16* __restrict__ out, int R, int C) {
  __shared__ bf16 tile[32][33];
  const int r0 = blockIdx.y * 32, c0 = blockIdx.x * 32;
  const int tid = threadIdx.x;
  const int c = tid & 31, r = tid >> 5;
#pragma unroll
  for (int rr = r; rr < 32; rr += 8)
    tile[rr][c] = (bf16)in[(size_t)(r0 + rr) * C + c0 + c];
  __syncthreads();
  const int oc = tid >> 3;           // out row within tile (0..31)
  const int ok = (tid & 7) * 4;      // out col chunk
  bf16x4 v;
#pragma unroll
  for (int j = 0; j < 4; ++j) v[j] = tile[ok + j][oc];
  *(bf16x4*)&out[(size_t)(c0 + oc) * R + r0 + ok] = v;
}

// ---------------------------------------------------------------------------
// GEMM: C[M][N] = A[M][K] (bf16, row-major) @ BT[N][K]^T (bf16) + bias
// m97 structure: 128x128 tile, BK=32, 4 waves, 4x4 frags of 16x16x32.
// EPI 0: scatter to per-head Q [BH][T][D], K [BH][T][D], V^T [BH][D][T]
// EPI 1: fp32 out [M][N]
template <int EPI>
__global__ __launch_bounds__(256) void gemm_bt(
    const bf16* __restrict__ A, const bf16* __restrict__ BT,
    const float* __restrict__ bias, int M, int N, int K,
    float* __restrict__ outf, bf16* __restrict__ qb, bf16* __restrict__ kb,
    bf16* __restrict__ vtb) {
  __shared__ bf16 As[128][32];
  __shared__ bf16 Bs[128][32];
  const int tid = threadIdx.x;
  const int lane = tid & 63;
  const int w = tid >> 6;
  const int wr = (w >> 1) * 64, wc = (w & 1) * 64;
  const int m0 = blockIdx.y * 128, n0 = blockIdx.x * 128;
  const int lr = lane & 15, lg = lane >> 4;

  f32x4 acc[4][4] = {};

  for (int k0 = 0; k0 < K; k0 += 32) {
    __syncthreads();
#pragma unroll
    for (int c = 0; c < 2; ++c) {
      const int off = tid * 16 + c * 4096;          // byte offset in 8KB tile
      const int row = off >> 6, col = (off & 63) >> 1;
      gload_lds16(A + (size_t)(m0 + row) * K + k0 + col,
                  (char*)As + (tid & ~63) * 16 + c * 4096);
      gload_lds16(BT + (size_t)(n0 + row) * K + k0 + col,
                  (char*)Bs + (tid & ~63) * 16 + c * 4096);
    }
    __syncthreads();
    bf16x8 af[4], bfr[4];
#pragma unroll
    for (int i = 0; i < 4; ++i) {
      af[i] = *(const bf16x8*)&As[wr + i * 16 + lr][lg * 8];
      bfr[i] = *(const bf16x8*)&Bs[wc + i * 16 + lr][lg * 8];
    }
#pragma unroll
    for (int mi = 0; mi < 4; ++mi)
#pragma unroll
      for (int ni = 0; ni < 4; ++ni)
        acc[mi][ni] = __builtin_amdgcn_mfma_f32_16x16x32_bf16(
            af[mi], bfr[ni], acc[mi][ni], 0, 0, 0);
  }

  // epilogue: C/D layout col=lane&15, row=(lane>>4)*4+r  [verified m89/m91]
#pragma unroll
  for (int mi = 0; mi < 4; ++mi) {
    const int mbase = m0 + wr + mi * 16 + lg * 4;
#pragma unroll
    for (int ni = 0; ni < 4; ++ni) {
      const int n = n0 + wc + ni * 16 + lr;
      const float bv = bias[n];
      if (EPI == 1) {
#pragma unroll
        for (int r = 0; r < 4; ++r)
          outf[(size_t)(mbase + r) * N + n] = acc[mi][ni][r] + bv;
      } else {
        const int which = n >> 11;           // 0=q 1=k 2=v
        const int cc = n & 2047, h = cc >> 7, d = cc & 127;
        const int b = mbase >> 11, t0 = mbase & 2047;  // 4-row group never
        const int bh = b * 16 + h;                     // crosses b boundary
        if (which == 2) {
          bf16x4 pk;
#pragma unroll
          for (int r = 0; r < 4; ++r) pk[r] = (bf16)(acc[mi][ni][r] + bv);
          *(bf16x4*)&vtb[((size_t)bh * 128 + d) * 2048 + t0] = pk;
        } else {
          bf16* dst = (which == 0) ? qb : kb;
#pragma unroll
          for (int r = 0; r < 4; ++r)
            dst[((size_t)bh * 2048 + t0 + r) * 128 + d] =
                (bf16)(acc[mi][ni][r] + bv);
        }
      }
    }
  }
}

// ---------------------------------------------------------------------------
// Flash attention, causal. grid = (T/64, B*H). 4 waves, each owns 16 q-rows.
// Q [BH][T][D] bf16, K [BH][T][D] bf16, V^T [BH][D][T] bf16.
// out -> ab [B*T][C] bf16 (proj GEMM A input).
__global__ __launch_bounds__(256) void attn_kernel(
    const bf16* __restrict__ qb, const bf16* __restrict__ kb,
    const bf16* __restrict__ vtb, bf16* __restrict__ ob) {
  __shared__ bf16 Ks[64][128];    // 16 KB
  __shared__ bf16 Vs[128][64];    // 16 KB (V^T rows=d, cols=t)
  __shared__ bf16 Ps[4][16][72];  // per-wave P, pad 64->72 (144B rows, 16B ok)
  const int tid = threadIdx.x, lane = tid & 63, w = tid >> 6;
  const int qt = blockIdx.x, bh = blockIdx.y;
  const int lr = lane & 15, lg = lane >> 4;
  const int q0 = qt * 64;
  const size_t base = (size_t)bh * (2048 * 128);

  // hoist Q fragments: A-operand rows = l%16, k = 8*(l/16)+e  (contig 8)
  bf16x8 qf[4];
  {
    const bf16* qp = qb + base + (size_t)(q0 + w * 16 + lr) * 128 + lg * 8;
#pragma unroll
    for (int kk = 0; kk < 4; ++kk) qf[kk] = *(const bf16x8*)(qp + kk * 32);
  }

  f32x4 o[8] = {};
  float mst[4], lst[4];
#pragma unroll
  for (int r = 0; r < 4; ++r) { mst[r] = -1e30f; lst[r] = 0.f; }

  for (int kt = 0; kt <= qt; ++kt) {
    __syncthreads();
#pragma unroll
    for (int c = 0; c < 4; ++c) {
      const int off = tid * 16 + c * 4096;  // byte offset in 16KB tile
      {
        const int row = off >> 8, byte = off & 255;  // K rows = 256B
        gload_lds16(
            (const char*)kb + (base + (size_t)(kt * 64 + row) * 128) * 2 + byte,
            (char*)Ks + (tid & ~63) * 16 + c * 4096);
      }
      {
        const int d = off >> 7, byte = off & 127;    // V^T tile rows = 128B
        gload_lds16(
            (const char*)vtb + (base + (size_t)d * 2048 + kt * 64) * 2 + byte,
            (char*)Vs + (tid & ~63) * 16 + c * 4096);
      }
    }
    __syncthreads();

    // S = Q K^T : B-operand col = l%16 -> K row j*16+lr
    f32x4 s[4] = {};
#pragma unroll
    for (int kk = 0; kk < 4; ++kk)
#pragma unroll
      for (int j = 0; j < 4; ++j) {
        const bf16x8 kf = *(const bf16x8*)&Ks[j * 16 + lr][kk * 32 + lg * 8];
        s[j] = __builtin_amdgcn_mfma_f32_16x16x32_bf16(qf[kk], kf, s[j], 0, 0, 0);
      }

    const bool diag = (kt == qt);
#pragma unroll
    for (int j = 0; j < 4; ++j)
#pragma unroll
      for (int r = 0; r < 4; ++r) {
        float v = s[j][r] * 0.08838834764831845f;  // 1/sqrt(128)
        if (diag) {
          const int qq = w * 16 + lg * 4 + r;  // q within tile (q0==kt*64)
          const int kk2 = j * 16 + lr;         // k within tile
          if (kk2 > qq) v = -1e30f;
        }
        s[j][r] = v;
      }

    // online softmax; a q-row lives in the 16 lanes of one lg-group
    float pmax[4], alpha[4], rsum[4];
#pragma unroll
    for (int r = 0; r < 4; ++r) {
      float pm = fmaxf(fmaxf(s[0][r], s[1][r]), fmaxf(s[2][r], s[3][r]));
      pm = fmaxf(pm, __shfl_xor(pm, 1, 16));
      pm = fmaxf(pm, __shfl_xor(pm, 2, 16));
      pm = fmaxf(pm, __shfl_xor(pm, 4, 16));
      pm = fmaxf(pm, __shfl_xor(pm, 8, 16));
      const float mnew = fmaxf(mst[r], pm);
      alpha[r] = __expf(mst[r] - mnew);
      mst[r] = mnew;
      rsum[r] = 0.f;
    }
#pragma unroll
    for (int j = 0; j < 4; ++j)
#pragma unroll
      for (int r = 0; r < 4; ++r) {
        const float p = __expf(s[j][r] - mst[r]);
        rsum[r] += p;
        Ps[w][lg * 4 + r][j * 16 + lr] = (bf16)p;
      }
#pragma unroll
    for (int r = 0; r < 4; ++r) {
      rsum[r] += __shfl_xor(rsum[r], 1, 16);
      rsum[r] += __shfl_xor(rsum[r], 2, 16);
      rsum[r] += __shfl_xor(rsum[r], 4, 16);
      rsum[r] += __shfl_xor(rsum[r], 8, 16);
      lst[r] = lst[r] * alpha[r] + rsum[r];
    }
#pragma unroll
    for (int n = 0; n < 8; ++n)
#pragma unroll
      for (int r = 0; r < 4; ++r) o[n][r] *= alpha[r];

    // P (via LDS) @ V : A-operand P rows = l%16
    bf16x8 pf[2];
#pragma unroll
    for (int kk = 0; kk < 2; ++kk)
      pf[kk] = *(const bf16x8*)&Ps[w][lr][kk * 32 + lg * 8];
#pragma unroll
    for (int n = 0; n < 8; ++n)
#pragma unroll
      for (int kk = 0; kk < 2; ++kk) {
        const bf16x8 vf = *(const bf16x8*)&Vs[n * 16 + lr][kk * 32 + lg * 8];
        o[n] = __builtin_amdgcn_mfma_f32_16x16x32_bf16(pf[kk], vf, o[n], 0, 0, 0);
      }
  }

  // write attn-out as bf16 [B*T][C]
  const int b = bh >> 4, h = bh & 15;
#pragma unroll
  for (int r = 0; r < 4; ++r) {
    const float inv = 1.0f / lst[r];
    const int t = q0 + w * 16 + lg * 4 + r;
    bf16* dst = ob + ((size_t)(b * 2048 + t)) * 2048 + h * 128;
#pragma unroll
    for (int n = 0; n < 8; ++n) dst[n * 16 + lr] = (bf16)(o[n][r] * inv);
  }
}

// ---------------------------------------------------------------------------
extern "C" void kernel_launch(void* const* d_in, const int* in_sizes, int n_in,
                              void* d_out, int out_size, void* d_ws,
                              size_t ws_size, hipStream_t stream) {
  const float* x = (const float*)d_in[0];      // [4,2048,2048]
  const float* Wqkv = (const float*)d_in[1];   // [2048,6144]
  const float* bqkv = (const float*)d_in[2];   // [6144]
  const float* Wproj = (const float*)d_in[3];  // [2048,2048]
  const float* bproj = (const float*)d_in[4];  // [2048]
  float* out = (float*)d_out;                  // [8192,2048] fp32

  char* ws = (char*)d_ws;  // needs ~192 MiB
  bf16* xb     = (bf16*)(ws);                  // 33554432 B  x bf16
  bf16* wqkvT  = (bf16*)(ws + 33554432);       // 25165824 B  Wqkv^T
  bf16* wprojT = (bf16*)(ws + 58720256);       //  8388608 B  Wproj^T
  bf16* qb     = (bf16*)(ws + 67108864);       // 33554432 B  Q [BH][T][D]
  bf16* kb     = (bf16*)(ws + 100663296);      // 33554432 B  K [BH][T][D]
  bf16* vtb    = (bf16*)(ws + 134217728);      // 33554432 B  V^T [BH][D][T]
  bf16* ab     = (bf16*)(ws + 167772160);      // 33554432 B  attn out bf16

  cast_f32_bf16<<<8192, 256, 0, stream>>>(x, xb, 2097152);
  transpose_cast<<<dim3(192, 64), 256, 0, stream>>>(Wqkv, wqkvT, 2048, 6144);
  transpose_cast<<<dim3(64, 64), 256, 0, stream>>>(Wproj, wprojT, 2048, 2048);
  gemm_bt<0><<<dim3(48, 64), 256, 0, stream>>>(xb, wqkvT, bqkv, 8192, 6144,
                                               2048, nullptr, qb, kb, vtb);
  attn_kernel<<<dim3(32, 64), 256, 0, stream>>>(qb, kb, vtb, ab);
  gemm_bt<1><<<dim3(16, 64), 256, 0, stream>>>(ab, wprojT, bproj, 8192, 2048,
                                               2048, out, nullptr, nullptr,
                                               nullptr);
}

// Round 2
// 696.858 us; speedup vs baseline: 1.3051x; 1.3051x over previous
//
#include <hip/hip_runtime.h>

// ---------------------------------------------------------------------------
// Fused MHA: qkv = x@Wqkv+b ; causal attention ; out = attn@Wproj+b
// B=4, T=2048, C=2048, H=16, D=128. fp32 in/out, bf16 MFMA internally.
// ---------------------------------------------------------------------------

typedef __bf16 bf16;
typedef __bf16 bf16x8 __attribute__((ext_vector_type(8)));
typedef __bf16 bf16x4 __attribute__((ext_vector_type(4)));
typedef float f32x4 __attribute__((ext_vector_type(4)));

__device__ __forceinline__ void gload_lds16(const void* g, void* l) {
  __builtin_amdgcn_global_load_lds(
      (const __attribute__((address_space(1))) void*)g,
      (__attribute__((address_space(3))) void*)l, 16, 0, 0);
}

// ---------------------------------------------------------------------------
// cast fp32 -> bf16, 8 elems/thread
__global__ __launch_bounds__(256) void cast_f32_bf16(
    const float* __restrict__ in, bf16* __restrict__ out, int n8) {
  int i = blockIdx.x * 256 + threadIdx.x;
  if (i >= n8) return;
  const float4* p = (const float4*)in + (size_t)i * 2;
  float4 a = p[0], b = p[1];
  bf16x8 o8 = {(bf16)a.x, (bf16)a.y, (bf16)a.z, (bf16)a.w,
               (bf16)b.x, (bf16)b.y, (bf16)b.z, (bf16)b.w};
  *(bf16x8*)(out + (size_t)i * 8) = o8;
}

// ---------------------------------------------------------------------------
// W [R][C] fp32  ->  WT [C][R] bf16   (32x32 LDS tile transpose)
__global__ __launch_bounds__(256) void transpose_cast(
    const float* __restrict__ in, bf16* __restrict__ out, int R, int C) {
  __shared__ bf16 tile[32][33];
  const int r0 = blockIdx.y * 32, c0 = blockIdx.x * 32;
  const int tid = threadIdx.x;
  const int c = tid & 31, r = tid >> 5;
#pragma unroll
  for (int rr = r; rr < 32; rr += 8)
    tile[rr][c] = (bf16)in[(size_t)(r0 + rr) * C + c0 + c];
  __syncthreads();
  const int oc = tid >> 3;           // out row within tile (0..31)
  const int ok = (tid & 7) * 4;      // out col chunk
  bf16x4 v;
#pragma unroll
  for (int j = 0; j < 4; ++j) v[j] = tile[ok + j][oc];
  *(bf16x4*)&out[(size_t)(c0 + oc) * R + r0 + ok] = v;
}

// ---------------------------------------------------------------------------
// GEMM: C[M][N] = A[M][K] (bf16, row-major) @ BT[N][K]^T (bf16) + bias
// m97 structure: 128x128 tile, BK=32, 4 waves, 4x4 frags of 16x16x32.
// EPI 0: scatter to per-head Q [BH][T][D], K [BH][T][D], V^T [BH][D][T]
// EPI 1: fp32 out [M][N]
template <int EPI>
__global__ __launch_bounds__(256) void gemm_bt(
    const bf16* __restrict__ A, const bf16* __restrict__ BT,
    const float* __restrict__ bias, int M, int N, int K,
    float* __restrict__ outf, bf16* __restrict__ qb, bf16* __restrict__ kb,
    bf16* __restrict__ vtb) {
  __shared__ bf16 As[128][32];
  __shared__ bf16 Bs[128][32];
  const int tid = threadIdx.x;
  const int lane = tid & 63;
  const int w = tid >> 6;
  const int wr = (w >> 1) * 64, wc = (w & 1) * 64;
  const int m0 = blockIdx.y * 128, n0 = blockIdx.x * 128;
  const int lr = lane & 15, lg = lane >> 4;

  f32x4 acc[4][4] = {};

  for (int k0 = 0; k0 < K; k0 += 32) {
    __syncthreads();
#pragma unroll
    for (int c = 0; c < 2; ++c) {
      const int off = tid * 16 + c * 4096;          // byte offset in 8KB tile
      const int row = off >> 6, col = (off & 63) >> 1;
      gload_lds16(A + (size_t)(m0 + row) * K + k0 + col,
                  (char*)As + (tid & ~63) * 16 + c * 4096);
      gload_lds16(BT + (size_t)(n0 + row) * K + k0 + col,
                  (char*)Bs + (tid & ~63) * 16 + c * 4096);
    }
    __syncthreads();
    bf16x8 af[4], bfr[4];
#pragma unroll
    for (int i = 0; i < 4; ++i) {
      af[i] = *(const bf16x8*)&As[wr + i * 16 + lr][lg * 8];
      bfr[i] = *(const bf16x8*)&Bs[wc + i * 16 + lr][lg * 8];
    }
#pragma unroll
    for (int mi = 0; mi < 4; ++mi)
#pragma unroll
      for (int ni = 0; ni < 4; ++ni)
        acc[mi][ni] = __builtin_amdgcn_mfma_f32_16x16x32_bf16(
            af[mi], bfr[ni], acc[mi][ni], 0, 0, 0);
  }

  // epilogue: C/D layout col=lane&15, row=(lane>>4)*4+r  [verified m89/m91]
#pragma unroll
  for (int mi = 0; mi < 4; ++mi) {
    const int mbase = m0 + wr + mi * 16 + lg * 4;
#pragma unroll
    for (int ni = 0; ni < 4; ++ni) {
      const int n = n0 + wc + ni * 16 + lr;
      const float bv = bias[n];
      if (EPI == 1) {
#pragma unroll
        for (int r = 0; r < 4; ++r)
          outf[(size_t)(mbase + r) * N + n] = acc[mi][ni][r] + bv;
      } else {
        const int which = n >> 11;           // 0=q 1=k 2=v
        const int cc = n & 2047, h = cc >> 7, d = cc & 127;
        const int b = mbase >> 11, t0 = mbase & 2047;  // 4-row group never
        const int bh = b * 16 + h;                     // crosses b boundary
        if (which == 2) {
          bf16x4 pk;
#pragma unroll
          for (int r = 0; r < 4; ++r) pk[r] = (bf16)(acc[mi][ni][r] + bv);
          *(bf16x4*)&vtb[((size_t)bh * 128 + d) * 2048 + t0] = pk;
        } else {
          bf16* dst = (which == 0) ? qb : kb;
#pragma unroll
          for (int r = 0; r < 4; ++r)
            dst[((size_t)bh * 2048 + t0 + r) * 128 + d] =
                (bf16)(acc[mi][ni][r] + bv);
        }
      }
    }
  }
}

// ---------------------------------------------------------------------------
// Flash attention, causal. grid = (T/128, B*H). 4 waves; each wave owns two
// 16-row q-groups (g=0: rows q0..q0+63, g=1: rows q0+64..q0+127) sharing each
// staged K/V tile -> 64 MFMA / wave / 32KB staged.
// LDS K and V tiles are XOR-swizzled (elem ^= (row&7)<<3), staged via
// pre-swizzled per-lane GLOBAL source into linear gload_lds dest (rule #21).
// Q [BH][T][D] bf16, K [BH][T][D] bf16, V^T [BH][D][T] bf16.
__global__ __launch_bounds__(256) void attn_kernel(
    const bf16* __restrict__ qb, const bf16* __restrict__ kb,
    const bf16* __restrict__ vtb, bf16* __restrict__ ob) {
  __shared__ bf16 Ks[64 * 128];   // 16 KB, rows of 128 elems, swizzled
  __shared__ bf16 Vs[128 * 64];   // 16 KB, rows of 64 elems, swizzled
  __shared__ bf16 Ps[4][16][72];  // per-wave P, pad 64->72 (2-way free)
  const int tid = threadIdx.x, lane = tid & 63, w = tid >> 6;
  const int qt = blockIdx.x, bh = blockIdx.y;
  const int lr = lane & 15, lg = lane >> 4;
  const int q0 = qt * 128;
  const size_t base = (size_t)bh * (2048 * 128);
  const int rswz = (lr & 7) << 3;  // read-side XOR (element domain)

  // hoist Q frags; fold (1/sqrt(D))*log2(e) so softmax runs in exp2 domain
  const float qscale = 0.08838834764831845f * 1.4426950408889634f;
  bf16x8 qf[2][4];
#pragma unroll
  for (int g = 0; g < 2; ++g) {
    const bf16* qp =
        qb + base + (size_t)(q0 + g * 64 + w * 16 + lr) * 128 + lg * 8;
#pragma unroll
    for (int kk = 0; kk < 4; ++kk) {
      bf16x8 t = *(const bf16x8*)(qp + kk * 32);
#pragma unroll
      for (int e = 0; e < 8; ++e) t[e] = (bf16)((float)t[e] * qscale);
      qf[g][kk] = t;
    }
  }

  f32x4 o[2][8] = {};
  float mst[2][4], lst[2][4];
#pragma unroll
  for (int g = 0; g < 2; ++g)
#pragma unroll
    for (int r = 0; r < 4; ++r) { mst[g][r] = -1e30f; lst[g][r] = 0.f; }

  const int ntiles = 2 * qt + 2;
  for (int kt = 0; kt < ntiles; ++kt) {
    __syncthreads();
#pragma unroll
    for (int c = 0; c < 4; ++c) {
      const int L = w * 1024 + c * 4096 + lane * 16;  // lds byte offset
      {  // K tile: rows 256B. source col pre-XOR'd so swizzled-read is logical
        const int row = L >> 8, ce = (L & 255) >> 1;
        gload_lds16(kb + base + (size_t)(kt * 64 + row) * 128 +
                        (ce ^ ((row & 7) << 3)),
                    (char*)Ks + w * 1024 + c * 4096);
      }
      {  // V^T tile: rows 128B
        const int d = L >> 7, ce = (L & 127) >> 1;
        gload_lds16(vtb + base + (size_t)d * 2048 + kt * 64 +
                        (ce ^ ((d & 7) << 3)),
                    (char*)Vs + w * 1024 + c * 4096);
      }
    }
    __syncthreads();

#pragma unroll
    for (int g = 0; g < 2; ++g) {
      if (kt > 2 * qt + g) continue;  // uniform branch (kt,qt,g uniform)
      const bool diag = (kt == 2 * qt + g);

      // S = Q K^T : B-frag col=lr -> K row j*16+lr (swizzled read)
      f32x4 s[4] = {};
#pragma unroll
      for (int kk = 0; kk < 4; ++kk)
#pragma unroll
        for (int j = 0; j < 4; ++j) {
          const bf16x8 kf = *(const bf16x8*)&Ks[(j * 16 + lr) * 128 +
                                               ((kk * 32 + lg * 8) ^ rswz)];
          s[j] =
              __builtin_amdgcn_mfma_f32_16x16x32_bf16(qf[g][kk], kf, s[j], 0, 0, 0);
        }

      if (diag) {
#pragma unroll
        for (int j = 0; j < 4; ++j)
#pragma unroll
          for (int r = 0; r < 4; ++r) {
            const int qq = w * 16 + lg * 4 + r;
            if (j * 16 + lr > qq) s[j][r] = -1e30f;
          }
      }

      // online softmax (exp2 domain); q-row = 16 lanes of one lg-group
      float pmax[4];
#pragma unroll
      for (int r = 0; r < 4; ++r) {
        float pm = fmaxf(fmaxf(s[0][r], s[1][r]), fmaxf(s[2][r], s[3][r]));
        pm = fmaxf(pm, __shfl_xor(pm, 1, 16));
        pm = fmaxf(pm, __shfl_xor(pm, 2, 16));
        pm = fmaxf(pm, __shfl_xor(pm, 4, 16));
        pm = fmaxf(pm, __shfl_xor(pm, 8, 16));
        pmax[r] = pm;
      }
      bool need = false;
#pragma unroll
      for (int r = 0; r < 4; ++r) need |= (pmax[r] > mst[g][r]);
      if (__any(need)) {  // skip rescale pass when no row's max grew (exact)
#pragma unroll
        for (int r = 0; r < 4; ++r) {
          const float mnew = fmaxf(mst[g][r], pmax[r]);
          const float alpha = __builtin_amdgcn_exp2f(mst[g][r] - mnew);
          mst[g][r] = mnew;
          lst[g][r] *= alpha;
#pragma unroll
          for (int n = 0; n < 8; ++n) o[g][n][r] *= alpha;
        }
      }
      float rsum[4] = {0.f, 0.f, 0.f, 0.f};
#pragma unroll
      for (int j = 0; j < 4; ++j)
#pragma unroll
        for (int r = 0; r < 4; ++r) {
          const float p = __builtin_amdgcn_exp2f(s[j][r] - mst[g][r]);
          rsum[r] += p;
          Ps[w][lg * 4 + r][j * 16 + lr] = (bf16)p;
        }
#pragma unroll
      for (int r = 0; r < 4; ++r) {
        rsum[r] += __shfl_xor(rsum[r], 1, 16);
        rsum[r] += __shfl_xor(rsum[r], 2, 16);
        rsum[r] += __shfl_xor(rsum[r], 4, 16);
        rsum[r] += __shfl_xor(rsum[r], 8, 16);
        lst[g][r] += rsum[r];
      }

      // P (via per-wave LDS, within-wave ordering) @ V (swizzled read)
      bf16x8 pf[2];
#pragma unroll
      for (int kk = 0; kk < 2; ++kk)
        pf[kk] = *(const bf16x8*)&Ps[w][lr][kk * 32 + lg * 8];
#pragma unroll
      for (int n = 0; n < 8; ++n)
#pragma unroll
        for (int kk = 0; kk < 2; ++kk) {
          const bf16x8 vf = *(const bf16x8*)&Vs[(n * 16 + lr) * 64 +
                                               ((kk * 32 + lg * 8) ^ rswz)];
          o[g][n] =
              __builtin_amdgcn_mfma_f32_16x16x32_bf16(pf[kk], vf, o[g][n], 0, 0, 0);
        }
    }
  }

  // write attn-out as bf16 [B*T][C]
  const int b = bh >> 4, h = bh & 15;
#pragma unroll
  for (int g = 0; g < 2; ++g)
#pragma unroll
    for (int r = 0; r < 4; ++r) {
      const float inv = 1.0f / lst[g][r];
      const int t = q0 + g * 64 + w * 16 + lg * 4 + r;
      bf16* dst = ob + ((size_t)(b * 2048 + t)) * 2048 + h * 128;
#pragma unroll
      for (int n = 0; n < 8; ++n) dst[n * 16 + lr] = (bf16)(o[g][n][r] * inv);
    }
}

// ---------------------------------------------------------------------------
extern "C" void kernel_launch(void* const* d_in, const int* in_sizes, int n_in,
                              void* d_out, int out_size, void* d_ws,
                              size_t ws_size, hipStream_t stream) {
  const float* x = (const float*)d_in[0];      // [4,2048,2048]
  const float* Wqkv = (const float*)d_in[1];   // [2048,6144]
  const float* bqkv = (const float*)d_in[2];   // [6144]
  const float* Wproj = (const float*)d_in[3];  // [2048,2048]
  const float* bproj = (const float*)d_in[4];  // [2048]
  float* out = (float*)d_out;                  // [8192,2048] fp32

  char* ws = (char*)d_ws;  // needs ~192 MiB
  bf16* xb     = (bf16*)(ws);                  // 33554432 B  x bf16
  bf16* wqkvT  = (bf16*)(ws + 33554432);       // 25165824 B  Wqkv^T
  bf16* wprojT = (bf16*)(ws + 58720256);       //  8388608 B  Wproj^T
  bf16* qb     = (bf16*)(ws + 67108864);       // 33554432 B  Q [BH][T][D]
  bf16* kb     = (bf16*)(ws + 100663296);      // 33554432 B  K [BH][T][D]
  bf16* vtb    = (bf16*)(ws + 134217728);      // 33554432 B  V^T [BH][D][T]
  bf16* ab     = (bf16*)(ws + 167772160);      // 33554432 B  attn out bf16

  cast_f32_bf16<<<8192, 256, 0, stream>>>(x, xb, 2097152);
  transpose_cast<<<dim3(192, 64), 256, 0, stream>>>(Wqkv, wqkvT, 2048, 6144);
  transpose_cast<<<dim3(64, 64), 256, 0, stream>>>(Wproj, wprojT, 2048, 2048);
  gemm_bt<0><<<dim3(48, 64), 256, 0, stream>>>(xb, wqkvT, bqkv, 8192, 6144,
                                               2048, nullptr, qb, kb, vtb);
  attn_kernel<<<dim3(16, 64), 256, 0, stream>>>(qb, kb, vtb, ab);
  gemm_bt<1><<<dim3(16, 64), 256, 0, stream>>>(ab, wprojT, bproj, 8192, 2048,
                                               2048, out, nullptr, nullptr,
                                               nullptr);
}